// Round 4
// baseline (409.609 us; speedup 1.0000x reference)
//
#include <hip/hip_runtime.h>

#define MMOD 8
#define BB 8192
#define DD 256

typedef unsigned short u16;
typedef __attribute__((ext_vector_type(8))) short s16x8;
typedef __attribute__((ext_vector_type(4))) float f32x4;
typedef __attribute__((ext_vector_type(4))) unsigned short u16x4;

__device__ __forceinline__ float b2f(u16 u){ union{unsigned i; float f;} x; x.i=((unsigned)u)<<16; return x.f; }
__device__ __forceinline__ u16 f2b(float f){ union{float f; unsigned i;} x; x.f=f; unsigned r = x.i + 0x7FFF + ((x.i>>16)&1u); return (u16)(r>>16); }

// ---------------- dtype detection ----------------
// fp32 data: low 16 bits of each word are mantissa bits -> bf16-exponent uniform -> mostly insane.
// bf16 data: low 16 bits are a real N(0,1) bf16 -> exponent in [100,134] or zero.
__global__ void detect_kernel(const unsigned* x, int* flag){
  __shared__ int cnt[256];
  int tid = threadIdx.x;
  int c = 0;
  for (int i = tid; i < 4096; i += 256){
    unsigned w = x[i];
    unsigned lo = w & 0xFFFFu;
    unsigned e = (lo >> 7) & 0xFFu;
    if (lo == 0u || (e >= 100u && e <= 134u)) c++;
  }
  cnt[tid] = c;
  __syncthreads();
  for (int s = 128; s > 0; s >>= 1){
    if (tid < s) cnt[tid] += cnt[tid+s];
    __syncthreads();
  }
  if (tid == 0) *flag = (cnt[0] < 2048) ? 1 : 0;   // 1 = inputs are fp32
}

// ---------------- input conversion to canonical bf16 ----------------
struct ConvArgs {
  const void* src[10];
  u16*        dst[10];
  int         n[10];
  const int*  flag;
};
__global__ void convert_kernel(ConvArgs a){
  const bool f32 = (*a.flag != 0);
  const long long stride = (long long)gridDim.x * blockDim.x;
  const long long base   = (long long)blockIdx.x * blockDim.x + threadIdx.x;
  for (int s = 0; s < 10; s++){
    const int n  = a.n[s];
    const int n4 = n >> 2;
    u16* dst = a.dst[s];
    if (f32){
      const float* sp = (const float*)a.src[s];
      for (long long i = base; i < n4; i += stride){
        float4 v = ((const float4*)sp)[i];
        u16x4 p;
        p[0]=f2b(v.x); p[1]=f2b(v.y); p[2]=f2b(v.z); p[3]=f2b(v.w);
        *(u16x4*)(dst + (i<<2)) = p;
      }
      for (long long i = ((long long)n4<<2) + base; i < n; i += stride)
        dst[i] = f2b(sp[i]);
    } else {
      const u16* sp = (const u16*)a.src[s];
      for (long long i = base; i < n4; i += stride)
        *(u16x4*)(dst + (i<<2)) = ((const u16x4*)sp)[i];
      for (long long i = ((long long)n4<<2) + base; i < n; i += stride)
        dst[i] = sp[i];
    }
  }
}

// dtype-branchy 8-element load (idx is an element index, must be 8-aligned)
__device__ __forceinline__ s16x8 load8_any(const void* p, long long idx, bool f32){
  if (f32){
    const float* fp = (const float*)p;
    float4 lo = *(const float4*)(fp + idx);
    float4 hi = *(const float4*)(fp + idx + 4);
    s16x8 r;
    r[0]=(short)f2b(lo.x); r[1]=(short)f2b(lo.y); r[2]=(short)f2b(lo.z); r[3]=(short)f2b(lo.w);
    r[4]=(short)f2b(hi.x); r[5]=(short)f2b(hi.y); r[6]=(short)f2b(hi.z); r[7]=(short)f2b(hi.w);
    return r;
  }
  return *(const s16x8*)((const u16*)p + idx);
}

struct GArgs {
  const u16* A;  long long a_z; long long a_piece; int lda;  // A + z*a_z + (k>>8)*a_piece + b*lda + (k&255)
  const u16* A2; long long a2_z;                             // if non-null: base for k>=256
  const u16* B;  long long b_z; int ldb;                     // B + z*b_z + n*ldb + k   ([N,K] layout)
  u16*       C;  long long c_z; long long c_npiece; int ldc; // C + z*c_z + (n>>8)*c_npiece + b*ldc + (n&255)
  const u16* bias; long long bias_z;   // bf16 bias[n] (per z), optional
  const float* cbias;                  // fp32 bias[global n], optional
  float scale;
  int K;
  int relu;
};

// 128x128 tile, BK=64, 256 threads (4 waves), bf16 MFMA 16x16x32, fp32 acc.
// LDS layout: row r (128), true k-chunk q (8 x 8elem) stored at chunk (r*8 + (q ^ (r&7))).
__global__ __launch_bounds__(256, 2) void gemm_bt(GArgs g){
  alignas(16) __shared__ u16 lA[128*64];
  alignas(16) __shared__ u16 lB[128*64];
  const int tid  = threadIdx.x;
  const int lane = tid & 63;
  const int w    = tid >> 6;
  const int z    = blockIdx.z;

  const u16* Bbase = g.B + (long long)z * g.b_z + (long long)(blockIdx.y * 128) * g.ldb;

  f32x4 acc[4][4];
  #pragma unroll
  for (int i=0;i<4;i++)
    #pragma unroll
    for (int j=0;j<4;j++)
      #pragma unroll
      for (int r=0;r<4;r++) acc[i][j][r] = 0.0f;

  const int wr = (w >> 1) * 64, wc = (w & 1) * 64;
  const int fm = lane & 15;
  const int fk = (lane >> 4) * 8;
  const long long arow0 = (long long)blockIdx.x * 128;

  int srow[4], sq[4];
  #pragma unroll
  for (int i=0;i<4;i++){
    int c = i*256 + tid;
    srow[i] = c >> 3;
    sq[i]   = (c & 7) ^ (srow[i] & 7);
  }

  for (int k0 = 0; k0 < g.K; k0 += 64){
    const u16* Abase0 = (g.A2 && k0 >= 256) ? (g.A2 + (long long)z * g.a2_z)
                                            : (g.A  + (long long)z * g.a_z);
    const u16* At = Abase0 + (long long)(k0 >> 8) * g.a_piece + (k0 & 255);
    const u16* Bt = Bbase + k0;
    s16x8 va[4], vb[4];
    #pragma unroll
    for (int i=0;i<4;i++){
      va[i] = *(const s16x8*)(At + (arow0 + srow[i]) * (long long)g.lda + sq[i]*8);
      vb[i] = *(const s16x8*)(Bt + (long long)srow[i] * g.ldb + sq[i]*8);
    }
    __syncthreads();
    #pragma unroll
    for (int i=0;i<4;i++){
      int c = i*256 + tid;
      *(s16x8*)(lA + c*8) = va[i];
      *(s16x8*)(lB + c*8) = vb[i];
    }
    __syncthreads();
    #pragma unroll
    for (int kk = 0; kk < 64; kk += 32){
      s16x8 af[4], bfr[4];
      const int qf = (kk + fk) >> 3;
      #pragma unroll
      for (int mi=0; mi<4; mi++){
        int r = wr + mi*16 + fm;
        af[mi] = *(const s16x8*)(lA + (r*8 + (qf ^ (r & 7))) * 8);
      }
      #pragma unroll
      for (int ni=0; ni<4; ni++){
        int r = wc + ni*16 + fm;
        bfr[ni] = *(const s16x8*)(lB + (r*8 + (qf ^ (r & 7))) * 8);
      }
      #pragma unroll
      for (int mi=0; mi<4; mi++)
        #pragma unroll
        for (int ni=0; ni<4; ni++)
          acc[mi][ni] = __builtin_amdgcn_mfma_f32_16x16x32_bf16(af[mi], bfr[ni], acc[mi][ni], 0, 0, 0);
    }
  }
  __syncthreads();

  u16* Cb = g.C + (long long)z * g.c_z;
  const u16* biasp = g.bias ? g.bias + (long long)z * g.bias_z : (const u16*)0;
  #pragma unroll
  for (int mi=0; mi<4; mi++){
    #pragma unroll
    for (int ni=0; ni<4; ni++){
      int n = blockIdx.y*128 + wc + ni*16 + fm;
      float bb = 0.0f;
      if (g.cbias) bb = g.cbias[n];
      else if (biasp) bb = b2f(biasp[n]);
      long long cn = ((long long)(n >> 8)) * g.c_npiece + (n & 255);
      #pragma unroll
      for (int r=0; r<4; r++){
        long long b = arow0 + wr + mi*16 + (lane>>4)*4 + r;
        float v = acc[mi][ni][r] * g.scale + bb;
        if (g.relu) v = v > 0.0f ? v : 0.0f;
        Cb[cn + b * (long long)g.ldc] = f2b(v);
      }
    }
  }
}

// WB[n=(s*256+o)][k=(t*256+d)] = sum_e Wo[s,t,o,e]*Wv[s,t,e,d], zeroed on s==t diagonal.
// grid (2,2,64): x = o-tile, y = d-tile, z = pair s*8+t. Reads Wo/Wv dtype-branchy.
__global__ __launch_bounds__(256, 2) void build_wb(const void* Wo, const void* Wv, u16* WB, const int* flag){
  alignas(16) __shared__ u16 lA[128*64];
  alignas(16) __shared__ u16 lB[128*64];
  const bool f32 = (*flag != 0);
  const int tid  = threadIdx.x;
  const int lane = tid & 63;
  const int w    = tid >> 6;
  const int z = blockIdx.z, s = z >> 3, t = z & 7;
  const long long zoff = (long long)z * 65536;

  f32x4 acc[4][4];
  #pragma unroll
  for (int i=0;i<4;i++)
    #pragma unroll
    for (int j=0;j<4;j++)
      #pragma unroll
      for (int r=0;r<4;r++) acc[i][j][r] = 0.0f;

  const int wr = (w >> 1) * 64, wc = (w & 1) * 64;
  const int fm = lane & 15;
  const int fk = (lane >> 4) * 8;

  int srow[4], sq[4];
  #pragma unroll
  for (int i=0;i<4;i++){
    int c = i*256 + tid;
    srow[i] = c >> 3;
    sq[i]   = (c & 7) ^ (srow[i] & 7);
  }

  for (int k0 = 0; k0 < 256; k0 += 64){
    s16x8 va[4], vt[4];
    #pragma unroll
    for (int i=0;i<4;i++){
      long long aidx = zoff + (long long)(blockIdx.x*128 + srow[i]) * 256 + k0 + sq[i]*8;
      va[i] = load8_any(Wo, aidx, f32);
    }
    #pragma unroll
    for (int j=0;j<4;j++){
      int id = j*256 + tid;
      int e  = id >> 4;
      int dc = (id & 15) * 8;
      long long bidx = zoff + (long long)(k0 + e) * 256 + blockIdx.y*128 + dc;
      vt[j] = load8_any(Wv, bidx, f32);
    }
    __syncthreads();
    #pragma unroll
    for (int i=0;i<4;i++){
      int c = i*256 + tid;
      *(s16x8*)(lA + c*8) = va[i];
    }
    #pragma unroll
    for (int j=0;j<4;j++){
      int id = j*256 + tid;
      int e  = id >> 4;
      int dc = (id & 15) * 8;
      #pragma unroll
      for (int u=0; u<8; u++){
        int d = dc + u;
        lB[(d*8 + ((e>>3) ^ (d & 7)))*8 + (e & 7)] = (u16)vt[j][u];
      }
    }
    __syncthreads();
    #pragma unroll
    for (int kk = 0; kk < 64; kk += 32){
      s16x8 af[4], bfr[4];
      const int qf = (kk + fk) >> 3;
      #pragma unroll
      for (int mi=0; mi<4; mi++){
        int r = wr + mi*16 + fm;
        af[mi] = *(const s16x8*)(lA + (r*8 + (qf ^ (r & 7))) * 8);
      }
      #pragma unroll
      for (int ni=0; ni<4; ni++){
        int r = wc + ni*16 + fm;
        bfr[ni] = *(const s16x8*)(lB + (r*8 + (qf ^ (r & 7))) * 8);
      }
      #pragma unroll
      for (int mi=0; mi<4; mi++)
        #pragma unroll
        for (int ni=0; ni<4; ni++)
          acc[mi][ni] = __builtin_amdgcn_mfma_f32_16x16x32_bf16(af[mi], bfr[ni], acc[mi][ni], 0, 0, 0);
    }
    __syncthreads();
  }
  const int diag = (s == t);
  #pragma unroll
  for (int mi=0; mi<4; mi++){
    #pragma unroll
    for (int ni=0; ni<4; ni++){
      int d = blockIdx.y*128 + wc + ni*16 + fm;
      #pragma unroll
      for (int r=0; r<4; r++){
        int o = blockIdx.x*128 + wr + mi*16 + (lane>>4)*4 + r;
        float v = diag ? 0.0f : acc[mi][ni][r];
        WB[(long long)(s*256 + o) * 2048 + t*256 + d] = f2b(v);
      }
    }
  }
}

// cb[s*256+o] += (1/7)*( dot(bv[s,t,:], Wo[s,t,o,:]) + bo[s,t,o] )  for t != s.
// grid(64): one (s,t) pair per block; thread = o. cb must be zeroed first.
__global__ void cb_kernel(const void* bv, const void* Wo, const void* bo, float* cb, const int* flag){
  const bool f32 = (*flag != 0);
  int z = blockIdx.x, s = z >> 3, t = z & 7;
  if (s == t) return;
  int o = threadIdx.x;
  long long wbase  = (long long)z * 65536 + (long long)o * 256;
  long long bvbase = (long long)z * 256;
  float acc = 0.0f;
  if (f32){
    const float* W  = (const float*)Wo;
    const float* BV = (const float*)bv;
    for (int e = 0; e < 256; e += 4){
      float4 wv4 = *(const float4*)(W + wbase + e);
      float4 bv4 = *(const float4*)(BV + bvbase + e);
      acc += wv4.x*bv4.x + wv4.y*bv4.y + wv4.z*bv4.z + wv4.w*bv4.w;
    }
    acc += ((const float*)bo)[(long long)z*256 + o];
  } else {
    const u16* W  = (const u16*)Wo;
    const u16* BV = (const u16*)bv;
    for (int e = 0; e < 256; e += 4){
      u16x4 wv4 = *(const u16x4*)(W + wbase + e);
      u16x4 bv4 = *(const u16x4*)(BV + bvbase + e);
      acc += b2f(wv4[0])*b2f(bv4[0]) + b2f(wv4[1])*b2f(bv4[1])
           + b2f(wv4[2])*b2f(bv4[2]) + b2f(wv4[3])*b2f(bv4[3]);
    }
    acc += b2f(((const u16*)bo)[(long long)z*256 + o]);
  }
  atomicAdd(&cb[s*256 + o], acc * (1.0f/7.0f));
}

// score[m,b] = sigmoid(dot(ch[m,b,:], wc2) + bc2); out[b,:] = (1/8) sum_m fused[m,b,:]*score[m,b]
__global__ __launch_bounds__(256) void final_gate(const u16* ch, const u16* fused,
                                                  const u16* wc2b, const u16* bc2b,
                                                  void* out, const int* flag){
  __shared__ float red[4];
  __shared__ float scores[8];
  const bool f32 = (*flag != 0);
  int b = blockIdx.x;
  int tid = threadIdx.x, lane = tid & 63, w = tid >> 6;
  float wv = b2f(wc2b[tid]);
  float bc2f = b2f(bc2b[0]);
  for (int m=0; m<8; m++){
    float p = b2f(ch[((long long)m*BB + b)*256 + tid]) * wv;
    #pragma unroll
    for (int off=32; off>0; off>>=1) p += __shfl_down(p, off);
    if (lane == 0) red[w] = p;
    __syncthreads();
    if (tid == 0){
      float ssum = red[0]+red[1]+red[2]+red[3] + bc2f;
      scores[m] = 1.0f / (1.0f + __expf(-ssum));
    }
    __syncthreads();
  }
  float acc = 0.0f;
  #pragma unroll
  for (int m=0; m<8; m++)
    acc += b2f(fused[((long long)m*BB + b)*256 + tid]) * scores[m];
  acc *= 0.125f;
  if (f32) ((float*)out)[(long long)b*256 + tid] = acc;
  else     ((u16*)out)[(long long)b*256 + tid] = f2b(acc);
}

extern "C" void kernel_launch(void* const* d_in, const int* in_sizes, int n_in,
                              void* d_out, int out_size, void* d_ws, size_t ws_size,
                              hipStream_t stream){
  const void* x   = d_in[0];
  const void* q   = d_in[1];
  const void* Wv  = d_in[2];
  const void* bv  = d_in[3];
  const void* Wo  = d_in[4];
  const void* bo  = d_in[5];
  const void* W1  = d_in[6];
  const void* b1  = d_in[7];
  const void* W2  = d_in[8];
  const void* b2  = d_in[9];
  const void* Wc1 = d_in[10];
  const void* bc1 = d_in[11];
  const void* wc2 = d_in[12];
  const void* bc2 = d_in[13];

  char* ws = (char*)d_ws;
  // byte offsets (peak ~111.3 MB); lifetime-aliased
  u16*   xb    = (u16*)(ws + 0LL);            // 32MB; dead after stage3 -> fused
  u16*   qb    = (u16*)(ws + 33554432LL);     // 4MB
  u16*   cross = (u16*)(ws + 37748736LL);     // 32MB; dead after stage3 -> ch
  u16*   hid   = (u16*)(ws + 71303168LL);     // 32MB
  u16*   WB    = (u16*)(ws + 104857600LL);    // 8MB
  u16*   W1b   = (u16*)(ws + 113246208LL);    // 2MB
  u16*   W2b   = (u16*)(ws + 115343360LL);    // 1MB
  u16*   Wc1b  = (u16*)(ws + 116391936LL);    // 256KB
  u16*   b1b   = (u16*)(ws + 116654080LL);    // 4KB
  u16*   b2b   = (u16*)(ws + 116658176LL);    // 4KB
  u16*   bc1b  = (u16*)(ws + 116662272LL);    // 512B
  u16*   wc2b  = (u16*)(ws + 116662784LL);    // 512B
  u16*   bc2b  = (u16*)(ws + 116663296LL);    // 64B
  int*   flag  = (int*)(ws + 116663360LL);    // 64B
  float* cb    = (float*)(ws + 116663424LL);  // 8KB
  u16*   fused = xb;
  u16*   ch    = cross;

  detect_kernel<<<1, 256, 0, stream>>>((const unsigned*)x, flag);

  ConvArgs ca{};
  ca.src[0]=x;   ca.dst[0]=xb;   ca.n[0]=MMOD*BB*DD;
  ca.src[1]=q;   ca.dst[1]=qb;   ca.n[1]=BB*DD;
  ca.src[2]=W1;  ca.dst[2]=W1b;  ca.n[2]=MMOD*DD*2*DD;
  ca.src[3]=W2;  ca.dst[3]=W2b;  ca.n[3]=MMOD*DD*DD;
  ca.src[4]=Wc1; ca.dst[4]=Wc1b; ca.n[4]=DD*2*DD;
  ca.src[5]=b1;  ca.dst[5]=b1b;  ca.n[5]=MMOD*DD;
  ca.src[6]=b2;  ca.dst[6]=b2b;  ca.n[6]=MMOD*DD;
  ca.src[7]=bc1; ca.dst[7]=bc1b; ca.n[7]=DD;
  ca.src[8]=wc2; ca.dst[8]=wc2b; ca.n[8]=DD;
  ca.src[9]=bc2; ca.dst[9]=bc2b; ca.n[9]=1;
  ca.flag = flag;
  convert_kernel<<<1024, 256, 0, stream>>>(ca);

  hipMemsetAsync(cb, 0, 2048*sizeof(float), stream);
  build_wb<<<dim3(2,2,64), 256, 0, stream>>>(Wo, Wv, WB, flag);
  cb_kernel<<<dim3(64), 256, 0, stream>>>(bv, Wo, bo, cb, flag);

  const long long BD = (long long)BB * DD;

  // Stage 2: cross[s,b,o] = (1/7) sum_k xb'[b,k] * WB[(s,o),k] + cb   (k = t*256+d)
  GArgs g2{};
  g2.A = xb; g2.a_z = 0; g2.a_piece = BD; g2.lda = 256; g2.A2 = 0; g2.a2_z = 0;
  g2.B = WB; g2.b_z = 0; g2.ldb = 2048;
  g2.C = cross; g2.c_z = 0; g2.c_npiece = BD; g2.ldc = 256;
  g2.bias = 0; g2.bias_z = 0; g2.cbias = cb;
  g2.scale = 1.0f/7.0f; g2.K = 2048; g2.relu = 0;
  gemm_bt<<<dim3(64,16,1), 256, 0, stream>>>(g2);

  // Stage 3: hid[m] = relu([xb[m] | cross[m]] @ W1[m]^T + b1[m])
  GArgs g3{};
  g3.A = xb; g3.a_z = BD; g3.a_piece = 0; g3.lda = 256; g3.A2 = cross; g3.a2_z = BD;
  g3.B = W1b; g3.b_z = (long long)DD*2*DD; g3.ldb = 512;
  g3.C = hid; g3.c_z = BD; g3.c_npiece = 0; g3.ldc = 256;
  g3.bias = b1b; g3.bias_z = 256; g3.cbias = 0;
  g3.scale = 1.0f; g3.K = 512; g3.relu = 1;
  gemm_bt<<<dim3(64,2,8), 256, 0, stream>>>(g3);

  // Stage 4: fused[m] = hid[m] @ W2[m]^T + b2[m]   (fused overwrites dead xb)
  GArgs g4{};
  g4.A = hid; g4.a_z = BD; g4.a_piece = 0; g4.lda = 256; g4.A2 = 0; g4.a2_z = 0;
  g4.B = W2b; g4.b_z = (long long)DD*DD; g4.ldb = 256;
  g4.C = fused; g4.c_z = BD; g4.c_npiece = 0; g4.ldc = 256;
  g4.bias = b2b; g4.bias_z = 256; g4.cbias = 0;
  g4.scale = 1.0f; g4.K = 256; g4.relu = 0;
  gemm_bt<<<dim3(64,2,8), 256, 0, stream>>>(g4);

  // Stage 5: ch[m] = relu([qb | fused[m]] @ Wc1^T + bc1)   (ch overwrites dead cross)
  GArgs g5{};
  g5.A = qb; g5.a_z = 0; g5.a_piece = 0; g5.lda = 256; g5.A2 = fused; g5.a2_z = BD;
  g5.B = Wc1b; g5.b_z = 0; g5.ldb = 512;
  g5.C = ch; g5.c_z = BD; g5.c_npiece = 0; g5.ldc = 256;
  g5.bias = bc1b; g5.bias_z = 0; g5.cbias = 0;
  g5.scale = 1.0f; g5.K = 512; g5.relu = 1;
  gemm_bt<<<dim3(64,2,8), 256, 0, stream>>>(g5);

  final_gate<<<dim3(BB), 256, 0, stream>>>(ch, fused, wc2b, bc2b, d_out, flag);

  (void)in_sizes; (void)n_in; (void)out_size; (void)ws_size;
}

// Round 5
// 380.951 us; speedup vs baseline: 1.0752x; 1.0752x over previous
//
#include <hip/hip_runtime.h>

#define MMOD 8
#define BB 8192
#define DD 256

typedef unsigned short u16;
typedef __attribute__((ext_vector_type(8))) short s16x8;
typedef __attribute__((ext_vector_type(4))) float f32x4;
typedef __attribute__((ext_vector_type(8))) unsigned short u16x8;

typedef __attribute__((address_space(3))) unsigned short lds_u16;
typedef __attribute__((address_space(1))) const unsigned short gl_u16;

__device__ __forceinline__ float b2f(u16 u){ union{unsigned i; float f;} x; x.i=((unsigned)u)<<16; return x.f; }
__device__ __forceinline__ u16 f2b(float f){ union{float f; unsigned i;} x; x.f=f; unsigned r = x.i + 0x7FFF + ((x.i>>16)&1u); return (u16)(r>>16); }

// async global->LDS: per-lane src address, LDS dest = wave-uniform base + lane*16B
__device__ __forceinline__ void async_cp16(const u16* g, u16* l){
  __builtin_amdgcn_global_load_lds((gl_u16*)g, (lds_u16*)l, 16, 0, 0);
}

// ---------------- fp32 -> bf16 conversion ----------------
struct ConvArgs {
  const float* src[10];
  u16*         dst[10];
  int          n[10];
};
__global__ void convert_kernel(ConvArgs a){
  const long long stride = (long long)gridDim.x * blockDim.x;
  const long long base   = (long long)blockIdx.x * blockDim.x + threadIdx.x;
  for (int s = 0; s < 10; s++){
    const int n  = a.n[s];
    const int n8 = n >> 3;
    const float* sp = a.src[s];
    u16* dst = a.dst[s];
    for (long long i = base; i < n8; i += stride){
      float4 lo = ((const float4*)sp)[i*2];
      float4 hi = ((const float4*)sp)[i*2+1];
      u16x8 p;
      p[0]=f2b(lo.x); p[1]=f2b(lo.y); p[2]=f2b(lo.z); p[3]=f2b(lo.w);
      p[4]=f2b(hi.x); p[5]=f2b(hi.y); p[6]=f2b(hi.z); p[7]=f2b(hi.w);
      *(u16x8*)(dst + (i<<3)) = p;
    }
    for (long long i = ((long long)n8<<3) + base; i < n; i += stride)
      dst[i] = f2b(sp[i]);
  }
}

__device__ __forceinline__ s16x8 load8_f32(const float* p, long long idx){
  float4 lo = *(const float4*)(p + idx);
  float4 hi = *(const float4*)(p + idx + 4);
  s16x8 r;
  r[0]=(short)f2b(lo.x); r[1]=(short)f2b(lo.y); r[2]=(short)f2b(lo.z); r[3]=(short)f2b(lo.w);
  r[4]=(short)f2b(hi.x); r[5]=(short)f2b(hi.y); r[6]=(short)f2b(hi.z); r[7]=(short)f2b(hi.w);
  return r;
}

struct GArgs {
  const u16* A;  long long a_z; long long a_piece; int lda;  // A + z*a_z + (k>>8)*a_piece + b*lda + (k&255)
  const u16* A2; long long a2_z;                             // if non-null: base for k>=256
  const u16* B;  long long b_z; int ldb;                     // B + z*b_z + n*ldb + k   ([N,K] layout)
  u16*       C;  long long c_z; long long c_npiece; int ldc; // C + z*c_z + (n>>8)*c_npiece + b*ldc + (n&255)
  const u16* bias; long long bias_z;   // bf16 bias[n] (per z), optional
  const float* cbias;                  // fp32 bias[global n], optional
  const u16* addm;                     // bf16 addend [b,256] (shared across z), optional
  float scale;
  int K;
  int relu;
};

// 128x128 tile, BK=64, 256 threads (4 waves), bf16 MFMA 16x16x32, fp32 acc.
// LDS layout: row r (128), true k-chunk q (8 x 8elem) stored at chunk (r*8 + (q ^ (r&7))).
// Staging via global_load_lds width=16, 2-barrier structure (m97 shape).
__global__ __launch_bounds__(256, 2) void gemm_bt(GArgs g){
  alignas(16) __shared__ u16 lA[128*64];
  alignas(16) __shared__ u16 lB[128*64];
  const int tid  = threadIdx.x;
  const int lane = tid & 63;
  const int w    = tid >> 6;
  const int z    = blockIdx.z;

  const u16* Bbase = g.B + (long long)z * g.b_z + (long long)(blockIdx.y * 128) * g.ldb;

  f32x4 acc[4][4];
  #pragma unroll
  for (int i=0;i<4;i++)
    #pragma unroll
    for (int j=0;j<4;j++)
      #pragma unroll
      for (int r=0;r<4;r++) acc[i][j][r] = 0.0f;

  const int wr = (w >> 1) * 64, wc = (w & 1) * 64;
  const int fm = lane & 15;
  const int fk = (lane >> 4) * 8;
  const long long arow0 = (long long)blockIdx.x * 128;

  const int sr = lane >> 3;            // row within the wave's 8-row staging group
  const int sq = (lane & 7) ^ sr;      // true k-chunk (XOR swizzle)

  for (int k0 = 0; k0 < g.K; k0 += 64){
    const u16* Abase0 = (g.A2 && k0 >= 256) ? (g.A2 + (long long)z * g.a2_z)
                                            : (g.A  + (long long)z * g.a_z);
    const u16* At = Abase0 + (long long)(k0 >> 8) * g.a_piece + (k0 & 255);
    const u16* Bt = Bbase + k0;
    __syncthreads();   // all waves done reading previous tile
    #pragma unroll
    for (int i=0;i<4;i++){
      int r = i*32 + w*8 + sr;
      u16* ldsb = lA + (i*256 + w*64) * 8;   // wave-uniform chunk base
      async_cp16(At + (arow0 + r) * (long long)g.lda + sq*8, ldsb);
      async_cp16(Bt + (long long)r * g.ldb + sq*8, lB + (i*256 + w*64) * 8);
    }
    __syncthreads();   // drains vmcnt (global_load_lds) -> tile visible
    #pragma unroll
    for (int kk = 0; kk < 64; kk += 32){
      s16x8 af[4], bfr[4];
      const int qf = (kk + fk) >> 3;
      #pragma unroll
      for (int mi=0; mi<4; mi++){
        int r = wr + mi*16 + fm;
        af[mi] = *(const s16x8*)(lA + (r*8 + (qf ^ (r & 7))) * 8);
      }
      #pragma unroll
      for (int ni=0; ni<4; ni++){
        int r = wc + ni*16 + fm;
        bfr[ni] = *(const s16x8*)(lB + (r*8 + (qf ^ (r & 7))) * 8);
      }
      #pragma unroll
      for (int mi=0; mi<4; mi++)
        #pragma unroll
        for (int ni=0; ni<4; ni++)
          acc[mi][ni] = __builtin_amdgcn_mfma_f32_16x16x32_bf16(af[mi], bfr[ni], acc[mi][ni], 0, 0, 0);
    }
  }

  u16* Cb = g.C + (long long)z * g.c_z;
  const u16* biasp = g.bias ? g.bias + (long long)z * g.bias_z : (const u16*)0;
  #pragma unroll
  for (int mi=0; mi<4; mi++){
    #pragma unroll
    for (int ni=0; ni<4; ni++){
      int n = blockIdx.y*128 + wc + ni*16 + fm;
      float bb = 0.0f;
      if (g.cbias) bb = g.cbias[n];
      else if (biasp) bb = b2f(biasp[n]);
      long long cn = ((long long)(n >> 8)) * g.c_npiece + (n & 255);
      #pragma unroll
      for (int r=0; r<4; r++){
        long long b = arow0 + wr + mi*16 + (lane>>4)*4 + r;
        float v = acc[mi][ni][r] * g.scale + bb;
        if (g.addm) v += b2f(g.addm[b*256 + n]);
        if (g.relu) v = v > 0.0f ? v : 0.0f;
        Cb[cn + b * (long long)g.ldc] = f2b(v);
      }
    }
  }
}

// WB[n=(s*256+o)][k=(t*256+d)] = sum_e Wo[s,t,o,e]*Wv[s,t,e,d], zeroed on s==t diagonal.
// grid (2,2,64): x = o-tile, y = d-tile, z = pair s*8+t. Reads fp32 Wo/Wv directly.
__global__ __launch_bounds__(256, 2) void build_wb(const float* Wo, const float* Wv, u16* WB){
  alignas(16) __shared__ u16 lA[128*64];
  alignas(16) __shared__ u16 lB[128*64];
  const int tid  = threadIdx.x;
  const int lane = tid & 63;
  const int w    = tid >> 6;
  const int z = blockIdx.z, s = z >> 3, t = z & 7;
  const long long zoff = (long long)z * 65536;

  f32x4 acc[4][4];
  #pragma unroll
  for (int i=0;i<4;i++)
    #pragma unroll
    for (int j=0;j<4;j++)
      #pragma unroll
      for (int r=0;r<4;r++) acc[i][j][r] = 0.0f;

  const int wr = (w >> 1) * 64, wc = (w & 1) * 64;
  const int fm = lane & 15;
  const int fk = (lane >> 4) * 8;

  int srow[4], sq[4];
  #pragma unroll
  for (int i=0;i<4;i++){
    int c = i*256 + tid;
    srow[i] = c >> 3;
    sq[i]   = (c & 7) ^ (srow[i] & 7);
  }

  for (int k0 = 0; k0 < 256; k0 += 64){
    s16x8 va[4], vt[4];
    #pragma unroll
    for (int i=0;i<4;i++){
      long long aidx = zoff + (long long)(blockIdx.x*128 + srow[i]) * 256 + k0 + sq[i]*8;
      va[i] = load8_f32(Wo, aidx);
    }
    #pragma unroll
    for (int j=0;j<4;j++){
      int id = j*256 + tid;
      int e  = id >> 4;
      int dc = (id & 15) * 8;
      long long bidx = zoff + (long long)(k0 + e) * 256 + blockIdx.y*128 + dc;
      vt[j] = load8_f32(Wv, bidx);
    }
    __syncthreads();
    #pragma unroll
    for (int i=0;i<4;i++){
      int c = i*256 + tid;
      *(s16x8*)(lA + c*8) = va[i];
    }
    #pragma unroll
    for (int j=0;j<4;j++){
      int id = j*256 + tid;
      int e  = id >> 4;
      int dc = (id & 15) * 8;
      #pragma unroll
      for (int u=0; u<8; u++){
        int d = dc + u;
        lB[(d*8 + ((e>>3) ^ (d & 7)))*8 + (e & 7)] = (u16)vt[j][u];
      }
    }
    __syncthreads();
    #pragma unroll
    for (int kk = 0; kk < 64; kk += 32){
      s16x8 af[4], bfr[4];
      const int qf = (kk + fk) >> 3;
      #pragma unroll
      for (int mi=0; mi<4; mi++){
        int r = wr + mi*16 + fm;
        af[mi] = *(const s16x8*)(lA + (r*8 + (qf ^ (r & 7))) * 8);
      }
      #pragma unroll
      for (int ni=0; ni<4; ni++){
        int r = wc + ni*16 + fm;
        bfr[ni] = *(const s16x8*)(lB + (r*8 + (qf ^ (r & 7))) * 8);
      }
      #pragma unroll
      for (int mi=0; mi<4; mi++)
        #pragma unroll
        for (int ni=0; ni<4; ni++)
          acc[mi][ni] = __builtin_amdgcn_mfma_f32_16x16x32_bf16(af[mi], bfr[ni], acc[mi][ni], 0, 0, 0);
    }
    __syncthreads();
  }
  const int diag = (s == t);
  #pragma unroll
  for (int mi=0; mi<4; mi++){
    #pragma unroll
    for (int ni=0; ni<4; ni++){
      int d = blockIdx.y*128 + wc + ni*16 + fm;
      #pragma unroll
      for (int r=0; r<4; r++){
        int o = blockIdx.x*128 + wr + mi*16 + (lane>>4)*4 + r;
        float v = diag ? 0.0f : acc[mi][ni][r];
        WB[(long long)(s*256 + o) * 2048 + t*256 + d] = f2b(v);
      }
    }
  }
}

// cb[s*256+o] += (1/7)*( dot(bv[s,t,:], Wo[s,t,o,:]) + bo[s,t,o] )  for t != s. cb zeroed first.
__global__ void cb_kernel(const float* bv, const float* Wo, const float* bo, float* cb){
  int z = blockIdx.x, s = z >> 3, t = z & 7;
  if (s == t) return;
  int o = threadIdx.x;
  long long wbase  = (long long)z * 65536 + (long long)o * 256;
  long long bvbase = (long long)z * 256;
  float acc = 0.0f;
  for (int e = 0; e < 256; e += 4){
    float4 wv4 = *(const float4*)(Wo + wbase + e);
    float4 bv4 = *(const float4*)(bv + bvbase + e);
    acc += wv4.x*bv4.x + wv4.y*bv4.y + wv4.z*bv4.z + wv4.w*bv4.w;
  }
  acc += bo[(long long)z*256 + o];
  atomicAdd(&cb[s*256 + o], acc * (1.0f/7.0f));
}

// score[m,b] = sigmoid(dot(ch[m,b,:], wc2) + bc2); out[b,:] = (1/8) sum_m fused[m,b,:]*score[m,b]
__global__ __launch_bounds__(256) void final_gate(const u16* ch, const u16* fused,
                                                  const u16* wc2b, const u16* bc2b, float* out){
  __shared__ float red[4];
  __shared__ float scores[8];
  int b = blockIdx.x;
  int tid = threadIdx.x, lane = tid & 63, w = tid >> 6;
  float wv = b2f(wc2b[tid]);
  float bc2f = b2f(bc2b[0]);
  for (int m=0; m<8; m++){
    float p = b2f(ch[((long long)m*BB + b)*256 + tid]) * wv;
    #pragma unroll
    for (int off=32; off>0; off>>=1) p += __shfl_down(p, off);
    if (lane == 0) red[w] = p;
    __syncthreads();
    if (tid == 0){
      float ssum = red[0]+red[1]+red[2]+red[3] + bc2f;
      scores[m] = 1.0f / (1.0f + __expf(-ssum));
    }
    __syncthreads();
  }
  float acc = 0.0f;
  #pragma unroll
  for (int m=0; m<8; m++)
    acc += b2f(fused[((long long)m*BB + b)*256 + tid]) * scores[m];
  out[(long long)b*256 + tid] = acc * 0.125f;
}

extern "C" void kernel_launch(void* const* d_in, const int* in_sizes, int n_in,
                              void* d_out, int out_size, void* d_ws, size_t ws_size,
                              hipStream_t stream){
  const float* x   = (const float*)d_in[0];
  const float* q   = (const float*)d_in[1];
  const float* Wv  = (const float*)d_in[2];
  const float* bv  = (const float*)d_in[3];
  const float* Wo  = (const float*)d_in[4];
  const float* bo  = (const float*)d_in[5];
  const float* W1  = (const float*)d_in[6];
  const float* b1  = (const float*)d_in[7];
  const float* W2  = (const float*)d_in[8];
  const float* b2  = (const float*)d_in[9];
  const float* Wc1 = (const float*)d_in[10];
  const float* bc1 = (const float*)d_in[11];
  const float* wc2 = (const float*)d_in[12];
  const float* bc2 = (const float*)d_in[13];

  char* ws = (char*)d_ws;
  // byte offsets (peak ~111.3 MB); lifetime-aliased
  u16*   xb    = (u16*)(ws + 0LL);            // 32MB; dead after stage3 -> fused
  u16*   qb    = (u16*)(ws + 33554432LL);     // 4MB
  u16*   cross = (u16*)(ws + 37748736LL);     // 32MB; dead after stage3 -> ch
  u16*   hid   = (u16*)(ws + 71303168LL);     // 32MB
  u16*   WB    = (u16*)(ws + 104857600LL);    // 8MB; dead after stage2 -> qctx
  u16*   W1b   = (u16*)(ws + 113246208LL);    // 2MB
  u16*   W2b   = (u16*)(ws + 115343360LL);    // 1MB
  u16*   Wc1b  = (u16*)(ws + 116391936LL);    // 256KB
  u16*   b1b   = (u16*)(ws + 116654080LL);    // 4KB
  u16*   b2b   = (u16*)(ws + 116658176LL);    // 4KB
  u16*   bc1b  = (u16*)(ws + 116662272LL);    // 512B
  u16*   wc2b  = (u16*)(ws + 116662784LL);    // 512B
  u16*   bc2b  = (u16*)(ws + 116663296LL);    // 64B
  float* cb    = (float*)(ws + 116663424LL);  // 8KB
  u16*   fused = xb;
  u16*   ch    = cross;
  u16*   qctx  = WB;   // 4MB, after stage2

  ConvArgs ca{};
  ca.src[0]=x;   ca.dst[0]=xb;   ca.n[0]=MMOD*BB*DD;
  ca.src[1]=q;   ca.dst[1]=qb;   ca.n[1]=BB*DD;
  ca.src[2]=W1;  ca.dst[2]=W1b;  ca.n[2]=MMOD*DD*2*DD;
  ca.src[3]=W2;  ca.dst[3]=W2b;  ca.n[3]=MMOD*DD*DD;
  ca.src[4]=Wc1; ca.dst[4]=Wc1b; ca.n[4]=DD*2*DD;
  ca.src[5]=b1;  ca.dst[5]=b1b;  ca.n[5]=MMOD*DD;
  ca.src[6]=b2;  ca.dst[6]=b2b;  ca.n[6]=MMOD*DD;
  ca.src[7]=bc1; ca.dst[7]=bc1b; ca.n[7]=DD;
  ca.src[8]=wc2; ca.dst[8]=wc2b; ca.n[8]=DD;
  ca.src[9]=bc2; ca.dst[9]=bc2b; ca.n[9]=1;
  convert_kernel<<<1024, 256, 0, stream>>>(ca);

  hipMemsetAsync(cb, 0, 2048*sizeof(float), stream);
  build_wb<<<dim3(2,2,64), 256, 0, stream>>>(Wo, Wv, WB);
  cb_kernel<<<dim3(64), 256, 0, stream>>>(bv, Wo, bo, cb);

  const long long BD = (long long)BB * DD;

  // Stage 2: cross[s,b,o] = (1/7) sum_k xb'[b,k] * WB[(s,o),k] + cb   (k = t*256+d)
  GArgs g2{};
  g2.A = xb; g2.a_z = 0; g2.a_piece = BD; g2.lda = 256; g2.A2 = 0; g2.a2_z = 0;
  g2.B = WB; g2.b_z = 0; g2.ldb = 2048;
  g2.C = cross; g2.c_z = 0; g2.c_npiece = BD; g2.ldc = 256;
  g2.bias = 0; g2.bias_z = 0; g2.cbias = cb; g2.addm = 0;
  g2.scale = 1.0f/7.0f; g2.K = 2048; g2.relu = 0;
  gemm_bt<<<dim3(64,16,1), 256, 0, stream>>>(g2);

  // Stage 5a: qctx = qb @ Wc1[:, :256]^T   (overwrites dead WB)
  GArgs g5a{};
  g5a.A = qb; g5a.a_z = 0; g5a.a_piece = 0; g5a.lda = 256; g5a.A2 = 0; g5a.a2_z = 0;
  g5a.B = Wc1b; g5a.b_z = 0; g5a.ldb = 512;
  g5a.C = qctx; g5a.c_z = 0; g5a.c_npiece = 0; g5a.ldc = 256;
  g5a.bias = 0; g5a.bias_z = 0; g5a.cbias = 0; g5a.addm = 0;
  g5a.scale = 1.0f; g5a.K = 256; g5a.relu = 0;
  gemm_bt<<<dim3(64,2,1), 256, 0, stream>>>(g5a);

  // Stage 3: hid[m] = relu([xb[m] | cross[m]] @ W1[m]^T + b1[m])
  GArgs g3{};
  g3.A = xb; g3.a_z = BD; g3.a_piece = 0; g3.lda = 256; g3.A2 = cross; g3.a2_z = BD;
  g3.B = W1b; g3.b_z = (long long)DD*2*DD; g3.ldb = 512;
  g3.C = hid; g3.c_z = BD; g3.c_npiece = 0; g3.ldc = 256;
  g3.bias = b1b; g3.bias_z = 256; g3.cbias = 0; g3.addm = 0;
  g3.scale = 1.0f; g3.K = 512; g3.relu = 1;
  gemm_bt<<<dim3(64,2,8), 256, 0, stream>>>(g3);

  // Stage 4: fused[m] = hid[m] @ W2[m]^T + b2[m]   (fused overwrites dead xb)
  GArgs g4{};
  g4.A = hid; g4.a_z = BD; g4.a_piece = 0; g4.lda = 256; g4.A2 = 0; g4.a2_z = 0;
  g4.B = W2b; g4.b_z = (long long)DD*DD; g4.ldb = 256;
  g4.C = fused; g4.c_z = BD; g4.c_npiece = 0; g4.ldc = 256;
  g4.bias = b2b; g4.bias_z = 256; g4.cbias = 0; g4.addm = 0;
  g4.scale = 1.0f; g4.K = 256; g4.relu = 0;
  gemm_bt<<<dim3(64,2,8), 256, 0, stream>>>(g4);

  // Stage 5b: ch[m] = relu(fused[m] @ Wc1[:, 256:]^T + qctx + bc1)   (ch overwrites dead cross)
  GArgs g5b{};
  g5b.A = fused; g5b.a_z = BD; g5b.a_piece = 0; g5b.lda = 256; g5b.A2 = 0; g5b.a2_z = 0;
  g5b.B = Wc1b + 256; g5b.b_z = 0; g5b.ldb = 512;
  g5b.C = ch; g5b.c_z = BD; g5b.c_npiece = 0; g5b.ldc = 256;
  g5b.bias = bc1b; g5b.bias_z = 0; g5b.cbias = 0; g5b.addm = qctx;
  g5b.scale = 1.0f; g5b.K = 256; g5b.relu = 1;
  gemm_bt<<<dim3(64,2,8), 256, 0, stream>>>(g5b);

  final_gate<<<dim3(BB), 256, 0, stream>>>(ch, fused, wc2b, bc2b, (float*)d_out);

  (void)in_sizes; (void)n_in; (void)out_size; (void)ws_size;
}

// Round 6
// 374.022 us; speedup vs baseline: 1.0951x; 1.0185x over previous
//
#include <hip/hip_runtime.h>

#define MMOD 8
#define BB 8192
#define DD 256

typedef unsigned short u16;
typedef __attribute__((ext_vector_type(8))) short s16x8;
typedef __attribute__((ext_vector_type(4))) float f32x4;
typedef __attribute__((ext_vector_type(8))) unsigned short u16x8;

typedef __attribute__((address_space(3))) unsigned short lds_u16;
typedef __attribute__((address_space(1))) const unsigned short gl_u16;

__device__ __forceinline__ float b2f(u16 u){ union{unsigned i; float f;} x; x.i=((unsigned)u)<<16; return x.f; }
__device__ __forceinline__ u16 f2b(float f){ union{float f; unsigned i;} x; x.f=f; unsigned r = x.i + 0x7FFF + ((x.i>>16)&1u); return (u16)(r>>16); }

// async global->LDS: per-lane src address, LDS dest = wave-uniform base + lane*16B
__device__ __forceinline__ void async_cp16(const u16* g, u16* l){
  __builtin_amdgcn_global_load_lds((gl_u16*)g, (lds_u16*)l, 16, 0, 0);
}

// ---------------- fp32 -> bf16 conversion ----------------
struct ConvArgs {
  const float* src[10];
  u16*         dst[10];
  int          n[10];
};
__global__ void convert_kernel(ConvArgs a){
  const long long stride = (long long)gridDim.x * blockDim.x;
  const long long base   = (long long)blockIdx.x * blockDim.x + threadIdx.x;
  for (int s = 0; s < 10; s++){
    const int n  = a.n[s];
    const int n8 = n >> 3;
    const float* sp = a.src[s];
    u16* dst = a.dst[s];
    for (long long i = base; i < n8; i += stride){
      float4 lo = ((const float4*)sp)[i*2];
      float4 hi = ((const float4*)sp)[i*2+1];
      u16x8 p;
      p[0]=f2b(lo.x); p[1]=f2b(lo.y); p[2]=f2b(lo.z); p[3]=f2b(lo.w);
      p[4]=f2b(hi.x); p[5]=f2b(hi.y); p[6]=f2b(hi.z); p[7]=f2b(hi.w);
      *(u16x8*)(dst + (i<<3)) = p;
    }
    for (long long i = ((long long)n8<<3) + base; i < n; i += stride)
      dst[i] = f2b(sp[i]);
  }
}

__device__ __forceinline__ s16x8 load8_f32(const float* p, long long idx){
  float4 lo = *(const float4*)(p + idx);
  float4 hi = *(const float4*)(p + idx + 4);
  s16x8 r;
  r[0]=(short)f2b(lo.x); r[1]=(short)f2b(lo.y); r[2]=(short)f2b(lo.z); r[3]=(short)f2b(lo.w);
  r[4]=(short)f2b(hi.x); r[5]=(short)f2b(hi.y); r[6]=(short)f2b(hi.z); r[7]=(short)f2b(hi.w);
  return r;
}

struct GArgs {
  const u16* A;  long long a_z; long long a_piece; int lda;  // A + z*a_z + (k>>8)*a_piece + b*lda + (k&255)
  const u16* A2; long long a2_z;                             // if non-null: base for k>=256
  const u16* B;  long long b_z; int ldb;                     // B + z*b_z + n*ldb + k   ([N,K] layout)
  u16*       C;  long long c_z; long long c_npiece; int ldc; // C + z*c_z + (n>>8)*c_npiece + b*ldc + (n&255)
  const u16* bias; long long bias_z;   // bf16 bias[n] (per z), optional
  const float* cbias;                  // fp32 bias[global n], optional
  const u16* addm;                     // bf16 addend [b,256] (shared across z), optional
  float scale;
  int K;
  int relu;
};

// ---------- fat tile: 128x128, BK=64, for the big K=2048 GEMM ----------
__global__ __launch_bounds__(256, 2) void gemm_bt(GArgs g){
  alignas(16) __shared__ u16 lA[128*64];
  alignas(16) __shared__ u16 lB[128*64];
  const int tid  = threadIdx.x;
  const int lane = tid & 63;
  const int w    = tid >> 6;
  const int z    = blockIdx.z;

  const u16* Bbase = g.B + (long long)z * g.b_z + (long long)(blockIdx.y * 128) * g.ldb;

  f32x4 acc[4][4];
  #pragma unroll
  for (int i=0;i<4;i++)
    #pragma unroll
    for (int j=0;j<4;j++)
      #pragma unroll
      for (int r=0;r<4;r++) acc[i][j][r] = 0.0f;

  const int wr = (w >> 1) * 64, wc = (w & 1) * 64;
  const int fm = lane & 15;
  const int fk = (lane >> 4) * 8;
  const long long arow0 = (long long)blockIdx.x * 128;

  const int sr = lane >> 3;
  const int sq = (lane & 7) ^ sr;

  for (int k0 = 0; k0 < g.K; k0 += 64){
    const u16* Abase0 = (g.A2 && k0 >= 256) ? (g.A2 + (long long)z * g.a2_z)
                                            : (g.A  + (long long)z * g.a_z);
    const u16* At = Abase0 + (long long)(k0 >> 8) * g.a_piece + (k0 & 255);
    const u16* Bt = Bbase + k0;
    __syncthreads();
    #pragma unroll
    for (int i=0;i<4;i++){
      int r = i*32 + w*8 + sr;
      async_cp16(At + (arow0 + r) * (long long)g.lda + sq*8, lA + (i*256 + w*64) * 8);
      async_cp16(Bt + (long long)r * g.ldb + sq*8, lB + (i*256 + w*64) * 8);
    }
    __syncthreads();
    #pragma unroll
    for (int kk = 0; kk < 64; kk += 32){
      s16x8 af[4], bfr[4];
      const int qf = (kk + fk) >> 3;
      #pragma unroll
      for (int mi=0; mi<4; mi++){
        int r = wr + mi*16 + fm;
        af[mi] = *(const s16x8*)(lA + (r*8 + (qf ^ (r & 7))) * 8);
      }
      #pragma unroll
      for (int ni=0; ni<4; ni++){
        int r = wc + ni*16 + fm;
        bfr[ni] = *(const s16x8*)(lB + (r*8 + (qf ^ (r & 7))) * 8);
      }
      #pragma unroll
      for (int mi=0; mi<4; mi++)
        #pragma unroll
        for (int ni=0; ni<4; ni++)
          acc[mi][ni] = __builtin_amdgcn_mfma_f32_16x16x32_bf16(af[mi], bfr[ni], acc[mi][ni], 0, 0, 0);
    }
  }

  u16* Cb = g.C + (long long)z * g.c_z;
  const u16* biasp = g.bias ? g.bias + (long long)z * g.bias_z : (const u16*)0;
  #pragma unroll
  for (int mi=0; mi<4; mi++){
    #pragma unroll
    for (int ni=0; ni<4; ni++){
      int n = blockIdx.y*128 + wc + ni*16 + fm;
      float bb = 0.0f;
      if (g.cbias) bb = g.cbias[n];
      else if (biasp) bb = b2f(biasp[n]);
      long long cn = ((long long)(n >> 8)) * g.c_npiece + (n & 255);
      #pragma unroll
      for (int r=0; r<4; r++){
        long long b = arow0 + wr + mi*16 + (lane>>4)*4 + r;
        float v = acc[mi][ni][r] * g.scale + bb;
        if (g.addm) v += b2f(g.addm[b*256 + n]);
        if (g.relu) v = v > 0.0f ? v : 0.0f;
        Cb[cn + b * (long long)g.ldc] = f2b(v);
      }
    }
  }
}

// ---------- thin tile: 64x128, BK=64, for the short-K memory-bound GEMMs ----------
// wave w owns rows [w*16, w*16+16), all 128 n-cols (8 n-tiles). LDS 24KB -> ~5 blocks/CU.
__global__ __launch_bounds__(256, 4) void gemm_thin(GArgs g){
  alignas(16) __shared__ u16 lA[64*64];
  alignas(16) __shared__ u16 lB[128*64];
  const int tid  = threadIdx.x;
  const int lane = tid & 63;
  const int w    = tid >> 6;
  const int z    = blockIdx.z;

  const u16* Bbase = g.B + (long long)z * g.b_z + (long long)(blockIdx.y * 128) * g.ldb;

  f32x4 acc[8];
  #pragma unroll
  for (int j=0;j<8;j++)
    #pragma unroll
    for (int r=0;r<4;r++) acc[j][r] = 0.0f;

  const int fm = lane & 15;
  const int fk = (lane >> 4) * 8;
  const long long arow0 = (long long)blockIdx.x * 64;

  const int sr = lane >> 3;
  const int sq = (lane & 7) ^ sr;

  for (int k0 = 0; k0 < g.K; k0 += 64){
    const u16* Abase0 = (g.A2 && k0 >= 256) ? (g.A2 + (long long)z * g.a2_z)
                                            : (g.A  + (long long)z * g.a_z);
    const u16* At = Abase0 + (long long)(k0 >> 8) * g.a_piece + (k0 & 255);
    const u16* Bt = Bbase + k0;
    __syncthreads();
    // A: 64 rows x 8 chunks = 512 chunks; 2 rounds of 256
    #pragma unroll
    for (int i=0;i<2;i++){
      int r = i*32 + w*8 + sr;
      async_cp16(At + (arow0 + r) * (long long)g.lda + sq*8, lA + (i*256 + w*64) * 8);
    }
    // B: 128 rows x 8 chunks = 1024 chunks; 4 rounds
    #pragma unroll
    for (int i=0;i<4;i++){
      int r = i*32 + w*8 + sr;
      async_cp16(Bt + (long long)r * g.ldb + sq*8, lB + (i*256 + w*64) * 8);
    }
    __syncthreads();
    #pragma unroll
    for (int kk = 0; kk < 64; kk += 32){
      const int qf = (kk + fk) >> 3;
      int ra = w*16 + fm;
      s16x8 af = *(const s16x8*)(lA + (ra*8 + (qf ^ (ra & 7))) * 8);
      s16x8 bfr[8];
      #pragma unroll
      for (int ni=0; ni<8; ni++){
        int r = ni*16 + fm;
        bfr[ni] = *(const s16x8*)(lB + (r*8 + (qf ^ (r & 7))) * 8);
      }
      #pragma unroll
      for (int ni=0; ni<8; ni++)
        acc[ni] = __builtin_amdgcn_mfma_f32_16x16x32_bf16(af, bfr[ni], acc[ni], 0, 0, 0);
    }
  }

  u16* Cb = g.C + (long long)z * g.c_z;
  const u16* biasp = g.bias ? g.bias + (long long)z * g.bias_z : (const u16*)0;
  #pragma unroll
  for (int ni=0; ni<8; ni++){
    int n = blockIdx.y*128 + ni*16 + fm;
    float bb = 0.0f;
    if (g.cbias) bb = g.cbias[n];
    else if (biasp) bb = b2f(biasp[n]);
    long long cn = ((long long)(n >> 8)) * g.c_npiece + (n & 255);
    #pragma unroll
    for (int r=0; r<4; r++){
      long long b = arow0 + w*16 + (lane>>4)*4 + r;
      float v = acc[ni][r] * g.scale + bb;
      if (g.addm) v += b2f(g.addm[b*256 + n]);
      if (g.relu) v = v > 0.0f ? v : 0.0f;
      Cb[cn + b * (long long)g.ldc] = f2b(v);
    }
  }
}

// WB[n=(s*256+o)][k=(t*256+d)] = sum_e Wo[s,t,o,e]*Wv[s,t,e,d], zeroed on s==t diagonal.
__global__ __launch_bounds__(256, 2) void build_wb(const float* Wo, const float* Wv, u16* WB){
  alignas(16) __shared__ u16 lA[128*64];
  alignas(16) __shared__ u16 lB[128*64];
  const int tid  = threadIdx.x;
  const int lane = tid & 63;
  const int w    = tid >> 6;
  const int z = blockIdx.z, s = z >> 3, t = z & 7;
  const long long zoff = (long long)z * 65536;

  f32x4 acc[4][4];
  #pragma unroll
  for (int i=0;i<4;i++)
    #pragma unroll
    for (int j=0;j<4;j++)
      #pragma unroll
      for (int r=0;r<4;r++) acc[i][j][r] = 0.0f;

  const int wr = (w >> 1) * 64, wc = (w & 1) * 64;
  const int fm = lane & 15;
  const int fk = (lane >> 4) * 8;

  int srow[4], sq[4];
  #pragma unroll
  for (int i=0;i<4;i++){
    int c = i*256 + tid;
    srow[i] = c >> 3;
    sq[i]   = (c & 7) ^ (srow[i] & 7);
  }

  for (int k0 = 0; k0 < 256; k0 += 64){
    s16x8 va[4], vt[4];
    #pragma unroll
    for (int i=0;i<4;i++){
      long long aidx = zoff + (long long)(blockIdx.x*128 + srow[i]) * 256 + k0 + sq[i]*8;
      va[i] = load8_f32(Wo, aidx);
    }
    #pragma unroll
    for (int j=0;j<4;j++){
      int id = j*256 + tid;
      int e  = id >> 4;
      int dc = (id & 15) * 8;
      long long bidx = zoff + (long long)(k0 + e) * 256 + blockIdx.y*128 + dc;
      vt[j] = load8_f32(Wv, bidx);
    }
    __syncthreads();
    #pragma unroll
    for (int i=0;i<4;i++){
      int c = i*256 + tid;
      *(s16x8*)(lA + c*8) = va[i];
    }
    #pragma unroll
    for (int j=0;j<4;j++){
      int id = j*256 + tid;
      int e  = id >> 4;
      int dc = (id & 15) * 8;
      #pragma unroll
      for (int u=0; u<8; u++){
        int d = dc + u;
        lB[(d*8 + ((e>>3) ^ (d & 7)))*8 + (e & 7)] = (u16)vt[j][u];
      }
    }
    __syncthreads();
    #pragma unroll
    for (int kk = 0; kk < 64; kk += 32){
      s16x8 af[4], bfr[4];
      const int qf = (kk + fk) >> 3;
      #pragma unroll
      for (int mi=0; mi<4; mi++){
        int r = wr + mi*16 + fm;
        af[mi] = *(const s16x8*)(lA + (r*8 + (qf ^ (r & 7))) * 8);
      }
      #pragma unroll
      for (int ni=0; ni<4; ni++){
        int r = wc + ni*16 + fm;
        bfr[ni] = *(const s16x8*)(lB + (r*8 + (qf ^ (r & 7))) * 8);
      }
      #pragma unroll
      for (int mi=0; mi<4; mi++)
        #pragma unroll
        for (int ni=0; ni<4; ni++)
          acc[mi][ni] = __builtin_amdgcn_mfma_f32_16x16x32_bf16(af[mi], bfr[ni], acc[mi][ni], 0, 0, 0);
    }
    __syncthreads();
  }
  const int diag = (s == t);
  #pragma unroll
  for (int mi=0; mi<4; mi++){
    #pragma unroll
    for (int ni=0; ni<4; ni++){
      int d = blockIdx.y*128 + wc + ni*16 + fm;
      #pragma unroll
      for (int r=0; r<4; r++){
        int o = blockIdx.x*128 + wr + mi*16 + (lane>>4)*4 + r;
        float v = diag ? 0.0f : acc[mi][ni][r];
        WB[(long long)(s*256 + o) * 2048 + t*256 + d] = f2b(v);
      }
    }
  }
}

// cb[s*256+o] += (1/7)*( dot(bv[s,t,:], Wo[s,t,o,:]) + bo[s,t,o] )  for t != s. cb zeroed first.
__global__ void cb_kernel(const float* bv, const float* Wo, const float* bo, float* cb){
  int z = blockIdx.x, s = z >> 3, t = z & 7;
  if (s == t) return;
  int o = threadIdx.x;
  long long wbase  = (long long)z * 65536 + (long long)o * 256;
  long long bvbase = (long long)z * 256;
  float acc = 0.0f;
  for (int e = 0; e < 256; e += 4){
    float4 wv4 = *(const float4*)(Wo + wbase + e);
    float4 bv4 = *(const float4*)(bv + bvbase + e);
    acc += wv4.x*bv4.x + wv4.y*bv4.y + wv4.z*bv4.z + wv4.w*bv4.w;
  }
  acc += bo[(long long)z*256 + o];
  atomicAdd(&cb[s*256 + o], acc * (1.0f/7.0f));
}

// score[m,b] = sigmoid(dot(ch[m,b,:], wc2) + bc2); out[b,:] = (1/8) sum_m fused[m,b,:]*score[m,b]
// wave w reduces modalities w and w+4 (lane sums 4 strided dims, 64-lane shuffle tree); 1 barrier.
__global__ __launch_bounds__(256) void final_gate(const u16* ch, const u16* fused,
                                                  const u16* wc2b, const u16* bc2b, float* out){
  __shared__ float scores[8];
  int b = blockIdx.x;
  int tid = threadIdx.x, lane = tid & 63, w = tid >> 6;
  float bc2f = b2f(bc2b[0]);
  float wv[4];
  #pragma unroll
  for (int j=0;j<4;j++) wv[j] = b2f(wc2b[lane + 64*j]);
  #pragma unroll
  for (int half=0; half<2; half++){
    int m = w + half*4;
    const u16* cp = ch + ((long long)m*BB + b)*256;
    float p = 0.0f;
    #pragma unroll
    for (int j=0;j<4;j++) p += b2f(cp[lane + 64*j]) * wv[j];
    #pragma unroll
    for (int off=32; off>0; off>>=1) p += __shfl_down(p, off);
    if (lane == 0) scores[m] = 1.0f / (1.0f + __expf(-(p + bc2f)));
  }
  __syncthreads();
  float acc = 0.0f;
  #pragma unroll
  for (int m=0; m<8; m++)
    acc += b2f(fused[((long long)m*BB + b)*256 + tid]) * scores[m];
  out[(long long)b*256 + tid] = acc * 0.125f;
}

extern "C" void kernel_launch(void* const* d_in, const int* in_sizes, int n_in,
                              void* d_out, int out_size, void* d_ws, size_t ws_size,
                              hipStream_t stream){
  const float* x   = (const float*)d_in[0];
  const float* q   = (const float*)d_in[1];
  const float* Wv  = (const float*)d_in[2];
  const float* bv  = (const float*)d_in[3];
  const float* Wo  = (const float*)d_in[4];
  const float* bo  = (const float*)d_in[5];
  const float* W1  = (const float*)d_in[6];
  const float* b1  = (const float*)d_in[7];
  const float* W2  = (const float*)d_in[8];
  const float* b2  = (const float*)d_in[9];
  const float* Wc1 = (const float*)d_in[10];
  const float* bc1 = (const float*)d_in[11];
  const float* wc2 = (const float*)d_in[12];
  const float* bc2 = (const float*)d_in[13];

  char* ws = (char*)d_ws;
  u16*   xb    = (u16*)(ws + 0LL);            // 32MB; dead after stage3 -> fused
  u16*   qb    = (u16*)(ws + 33554432LL);     // 4MB
  u16*   cross = (u16*)(ws + 37748736LL);     // 32MB; dead after stage3 -> ch
  u16*   hid   = (u16*)(ws + 71303168LL);     // 32MB
  u16*   WB    = (u16*)(ws + 104857600LL);    // 8MB; dead after stage2 -> qctx
  u16*   W1b   = (u16*)(ws + 113246208LL);    // 2MB
  u16*   W2b   = (u16*)(ws + 115343360LL);    // 1MB
  u16*   Wc1b  = (u16*)(ws + 116391936LL);    // 256KB
  u16*   b1b   = (u16*)(ws + 116654080LL);    // 4KB
  u16*   b2b   = (u16*)(ws + 116658176LL);    // 4KB
  u16*   bc1b  = (u16*)(ws + 116662272LL);    // 512B
  u16*   wc2b  = (u16*)(ws + 116662784LL);    // 512B
  u16*   bc2b  = (u16*)(ws + 116663296LL);    // 64B
  float* cb    = (float*)(ws + 116663424LL);  // 8KB
  u16*   fused = xb;
  u16*   ch    = cross;
  u16*   qctx  = WB;

  ConvArgs ca{};
  ca.src[0]=x;   ca.dst[0]=xb;   ca.n[0]=MMOD*BB*DD;
  ca.src[1]=q;   ca.dst[1]=qb;   ca.n[1]=BB*DD;
  ca.src[2]=W1;  ca.dst[2]=W1b;  ca.n[2]=MMOD*DD*2*DD;
  ca.src[3]=W2;  ca.dst[3]=W2b;  ca.n[3]=MMOD*DD*DD;
  ca.src[4]=Wc1; ca.dst[4]=Wc1b; ca.n[4]=DD*2*DD;
  ca.src[5]=b1;  ca.dst[5]=b1b;  ca.n[5]=MMOD*DD;
  ca.src[6]=b2;  ca.dst[6]=b2b;  ca.n[6]=MMOD*DD;
  ca.src[7]=bc1; ca.dst[7]=bc1b; ca.n[7]=DD;
  ca.src[8]=wc2; ca.dst[8]=wc2b; ca.n[8]=DD;
  ca.src[9]=bc2; ca.dst[9]=bc2b; ca.n[9]=1;
  convert_kernel<<<1024, 256, 0, stream>>>(ca);

  hipMemsetAsync(cb, 0, 2048*sizeof(float), stream);
  build_wb<<<dim3(2,2,64), 256, 0, stream>>>(Wo, Wv, WB);
  cb_kernel<<<dim3(64), 256, 0, stream>>>(bv, Wo, bo, cb);

  const long long BD = (long long)BB * DD;

  // Stage 2 (fat): cross[s,b,o] = (1/7) sum_k xb'[b,k] * WB[(s,o),k] + cb
  GArgs g2{};
  g2.A = xb; g2.a_z = 0; g2.a_piece = BD; g2.lda = 256; g2.A2 = 0; g2.a2_z = 0;
  g2.B = WB; g2.b_z = 0; g2.ldb = 2048;
  g2.C = cross; g2.c_z = 0; g2.c_npiece = BD; g2.ldc = 256;
  g2.bias = 0; g2.bias_z = 0; g2.cbias = cb; g2.addm = 0;
  g2.scale = 1.0f/7.0f; g2.K = 2048; g2.relu = 0;
  gemm_bt<<<dim3(64,16,1), 256, 0, stream>>>(g2);

  // Stage 5a (thin): qctx = qb @ Wc1[:, :256]^T   (overwrites dead WB)
  GArgs g5a{};
  g5a.A = qb; g5a.a_z = 0; g5a.a_piece = 0; g5a.lda = 256; g5a.A2 = 0; g5a.a2_z = 0;
  g5a.B = Wc1b; g5a.b_z = 0; g5a.ldb = 512;
  g5a.C = qctx; g5a.c_z = 0; g5a.c_npiece = 0; g5a.ldc = 256;
  g5a.bias = 0; g5a.bias_z = 0; g5a.cbias = 0; g5a.addm = 0;
  g5a.scale = 1.0f; g5a.K = 256; g5a.relu = 0;
  gemm_thin<<<dim3(128,2,1), 256, 0, stream>>>(g5a);

  // Stage 3 (thin): hid[m] = relu([xb[m] | cross[m]] @ W1[m]^T + b1[m])
  GArgs g3{};
  g3.A = xb; g3.a_z = BD; g3.a_piece = 0; g3.lda = 256; g3.A2 = cross; g3.a2_z = BD;
  g3.B = W1b; g3.b_z = (long long)DD*2*DD; g3.ldb = 512;
  g3.C = hid; g3.c_z = BD; g3.c_npiece = 0; g3.ldc = 256;
  g3.bias = b1b; g3.bias_z = 256; g3.cbias = 0; g3.addm = 0;
  g3.scale = 1.0f; g3.K = 512; g3.relu = 1;
  gemm_thin<<<dim3(128,2,8), 256, 0, stream>>>(g3);

  // Stage 4 (thin): fused[m] = hid[m] @ W2[m]^T + b2[m]   (overwrites dead xb)
  GArgs g4{};
  g4.A = hid; g4.a_z = BD; g4.a_piece = 0; g4.lda = 256; g4.A2 = 0; g4.a2_z = 0;
  g4.B = W2b; g4.b_z = (long long)DD*DD; g4.ldb = 256;
  g4.C = fused; g4.c_z = BD; g4.c_npiece = 0; g4.ldc = 256;
  g4.bias = b2b; g4.bias_z = 256; g4.cbias = 0; g4.addm = 0;
  g4.scale = 1.0f; g4.K = 256; g4.relu = 0;
  gemm_thin<<<dim3(128,2,8), 256, 0, stream>>>(g4);

  // Stage 5b (thin): ch[m] = relu(fused[m] @ Wc1[:, 256:]^T + qctx + bc1)  (overwrites dead cross)
  GArgs g5b{};
  g5b.A = fused; g5b.a_z = BD; g5b.a_piece = 0; g5b.lda = 256; g5b.A2 = 0; g5b.a2_z = 0;
  g5b.B = Wc1b + 256; g5b.b_z = 0; g5b.ldb = 512;
  g5b.C = ch; g5b.c_z = BD; g5b.c_npiece = 0; g5b.ldc = 256;
  g5b.bias = bc1b; g5b.bias_z = 0; g5b.cbias = 0; g5b.addm = qctx;
  g5b.scale = 1.0f; g5b.K = 256; g5b.relu = 1;
  gemm_thin<<<dim3(128,2,8), 256, 0, stream>>>(g5b);

  final_gate<<<dim3(BB), 256, 0, stream>>>(ch, fused, wc2b, bc2b, (float*)d_out);

  (void)in_sizes; (void)n_in; (void)out_size; (void)ws_size;
}

// Round 7
// 348.969 us; speedup vs baseline: 1.1738x; 1.0718x over previous
//
#include <hip/hip_runtime.h>

#define MMOD 8
#define BB 8192
#define DD 256

typedef unsigned short u16;
typedef __attribute__((ext_vector_type(8))) short s16x8;
typedef __attribute__((ext_vector_type(4))) float f32x4;
typedef __attribute__((ext_vector_type(8))) unsigned short u16x8;

typedef __attribute__((address_space(3))) unsigned short lds_u16;
typedef __attribute__((address_space(1))) const unsigned short gl_u16;

__device__ __forceinline__ float b2f(u16 u){ union{unsigned i; float f;} x; x.i=((unsigned)u)<<16; return x.f; }
__device__ __forceinline__ u16 f2b(float f){ union{float f; unsigned i;} x; x.f=f; unsigned r = x.i + 0x7FFF + ((x.i>>16)&1u); return (u16)(r>>16); }

// async global->LDS: per-lane src address, LDS dest = wave-uniform base + lane*16B
__device__ __forceinline__ void async_cp16(const u16* g, u16* l){
  __builtin_amdgcn_global_load_lds((gl_u16*)g, (lds_u16*)l, 16, 0, 0);
}

// ---------------- fp32 -> bf16 conversion ----------------
struct ConvArgs {
  const float* src[10];
  u16*         dst[10];
  int          n[10];
};
__global__ void convert_kernel(ConvArgs a){
  const long long stride = (long long)gridDim.x * blockDim.x;
  const long long base   = (long long)blockIdx.x * blockDim.x + threadIdx.x;
  for (int s = 0; s < 10; s++){
    const int n  = a.n[s];
    const int n8 = n >> 3;
    const float* sp = a.src[s];
    u16* dst = a.dst[s];
    for (long long i = base; i < n8; i += stride){
      float4 lo = ((const float4*)sp)[i*2];
      float4 hi = ((const float4*)sp)[i*2+1];
      u16x8 p;
      p[0]=f2b(lo.x); p[1]=f2b(lo.y); p[2]=f2b(lo.z); p[3]=f2b(lo.w);
      p[4]=f2b(hi.x); p[5]=f2b(hi.y); p[6]=f2b(hi.z); p[7]=f2b(hi.w);
      *(u16x8*)(dst + (i<<3)) = p;
    }
    for (long long i = ((long long)n8<<3) + base; i < n; i += stride)
      dst[i] = f2b(sp[i]);
  }
}

__device__ __forceinline__ s16x8 load8_f32(const float* p, long long idx){
  float4 lo = *(const float4*)(p + idx);
  float4 hi = *(const float4*)(p + idx + 4);
  s16x8 r;
  r[0]=(short)f2b(lo.x); r[1]=(short)f2b(lo.y); r[2]=(short)f2b(lo.z); r[3]=(short)f2b(lo.w);
  r[4]=(short)f2b(hi.x); r[5]=(short)f2b(hi.y); r[6]=(short)f2b(hi.z); r[7]=(short)f2b(hi.w);
  return r;
}

struct GArgs {
  const u16* A;  long long a_z; long long a_piece; int lda;  // A + z*a_z + (k>>8)*a_piece + b*lda + (k&255)
  const u16* A2; long long a2_z;                             // if non-null: base for k>=256
  const u16* B;  long long b_z; int ldb;                     // B + z*b_z + n*ldb + k   ([N,K] layout)
  u16*       C;  long long c_z; long long c_npiece; int ldc; // C + z*c_z + (n>>8)*c_npiece + b*ldc + (n&255)
  const u16* bias; long long bias_z;   // bf16 bias[n] (per z), optional
  const float* cbias;                  // fp32 bias[global n], optional
  const u16* addm;                     // bf16 addend [b,256] (shared across z), optional
  const u16* wc2;                      // score kernel: bf16 [256]
  float*     scores;                   // score kernel: [z*8192 + b]
  float scale;
  int K;
  int relu;
};

// ---------- fat tile: 128x128, BK=64, for the big K=2048 GEMM ----------
__global__ __launch_bounds__(256, 2) void gemm_bt(GArgs g){
  alignas(16) __shared__ u16 lA[128*64];
  alignas(16) __shared__ u16 lB[128*64];
  const int tid  = threadIdx.x;
  const int lane = tid & 63;
  const int w    = tid >> 6;
  const int z    = blockIdx.z;

  const u16* Bbase = g.B + (long long)z * g.b_z + (long long)(blockIdx.y * 128) * g.ldb;

  f32x4 acc[4][4];
  #pragma unroll
  for (int i=0;i<4;i++)
    #pragma unroll
    for (int j=0;j<4;j++)
      #pragma unroll
      for (int r=0;r<4;r++) acc[i][j][r] = 0.0f;

  const int wr = (w >> 1) * 64, wc = (w & 1) * 64;
  const int fm = lane & 15;
  const int fk = (lane >> 4) * 8;
  const long long arow0 = (long long)blockIdx.x * 128;

  const int sr = lane >> 3;
  const int sq = (lane & 7) ^ sr;

  for (int k0 = 0; k0 < g.K; k0 += 64){
    const u16* Abase0 = (g.A2 && k0 >= 256) ? (g.A2 + (long long)z * g.a2_z)
                                            : (g.A  + (long long)z * g.a_z);
    const u16* At = Abase0 + (long long)(k0 >> 8) * g.a_piece + (k0 & 255);
    const u16* Bt = Bbase + k0;
    __syncthreads();
    #pragma unroll
    for (int i=0;i<4;i++){
      int r = i*32 + w*8 + sr;
      async_cp16(At + (arow0 + r) * (long long)g.lda + sq*8, lA + (i*256 + w*64) * 8);
      async_cp16(Bt + (long long)r * g.ldb + sq*8, lB + (i*256 + w*64) * 8);
    }
    __syncthreads();
    #pragma unroll
    for (int kk = 0; kk < 64; kk += 32){
      s16x8 af[4], bfr[4];
      const int qf = (kk + fk) >> 3;
      #pragma unroll
      for (int mi=0; mi<4; mi++){
        int r = wr + mi*16 + fm;
        af[mi] = *(const s16x8*)(lA + (r*8 + (qf ^ (r & 7))) * 8);
      }
      #pragma unroll
      for (int ni=0; ni<4; ni++){
        int r = wc + ni*16 + fm;
        bfr[ni] = *(const s16x8*)(lB + (r*8 + (qf ^ (r & 7))) * 8);
      }
      #pragma unroll
      for (int mi=0; mi<4; mi++)
        #pragma unroll
        for (int ni=0; ni<4; ni++)
          acc[mi][ni] = __builtin_amdgcn_mfma_f32_16x16x32_bf16(af[mi], bfr[ni], acc[mi][ni], 0, 0, 0);
    }
  }

  u16* Cb = g.C + (long long)z * g.c_z;
  const u16* biasp = g.bias ? g.bias + (long long)z * g.bias_z : (const u16*)0;
  #pragma unroll
  for (int mi=0; mi<4; mi++){
    #pragma unroll
    for (int ni=0; ni<4; ni++){
      int n = blockIdx.y*128 + wc + ni*16 + fm;
      float bb = 0.0f;
      if (g.cbias) bb = g.cbias[n];
      else if (biasp) bb = b2f(biasp[n]);
      long long cn = ((long long)(n >> 8)) * g.c_npiece + (n & 255);
      #pragma unroll
      for (int r=0; r<4; r++){
        long long b = arow0 + wr + mi*16 + (lane>>4)*4 + r;
        float v = acc[mi][ni][r] * g.scale + bb;
        if (g.addm) v += b2f(g.addm[b*256 + n]);
        if (g.relu) v = v > 0.0f ? v : 0.0f;
        Cb[cn + b * (long long)g.ldc] = f2b(v);
      }
    }
  }
}

// ---------- thin full-N tile: 64 rows x 256 cols, BK=64 ----------
// wave w owns rows [w*16, w*16+16), all 256 n-cols (16 n-tiles). LDS 40KB -> 4 blocks/CU.
__global__ __launch_bounds__(256, 4) void gemm_thin(GArgs g){
  alignas(16) __shared__ u16 lA[64*64];
  alignas(16) __shared__ u16 lB[256*64];
  const int tid  = threadIdx.x;
  const int lane = tid & 63;
  const int w    = tid >> 6;
  const int z    = blockIdx.z;

  const u16* Bbase = g.B + (long long)z * g.b_z;

  f32x4 acc[16];
  #pragma unroll
  for (int j=0;j<16;j++)
    #pragma unroll
    for (int r=0;r<4;r++) acc[j][r] = 0.0f;

  const int fm = lane & 15;
  const int fk = (lane >> 4) * 8;
  const long long arow0 = (long long)blockIdx.x * 64;

  const int sr = lane >> 3;
  const int sq = (lane & 7) ^ sr;

  for (int k0 = 0; k0 < g.K; k0 += 64){
    const u16* Abase0 = (g.A2 && k0 >= 256) ? (g.A2 + (long long)z * g.a2_z)
                                            : (g.A  + (long long)z * g.a_z);
    const u16* At = Abase0 + (long long)(k0 >> 8) * g.a_piece + (k0 & 255);
    const u16* Bt = Bbase + k0;
    __syncthreads();
    #pragma unroll
    for (int i=0;i<2;i++){
      int r = i*32 + w*8 + sr;
      async_cp16(At + (arow0 + r) * (long long)g.lda + sq*8, lA + (i*256 + w*64) * 8);
    }
    #pragma unroll
    for (int i=0;i<8;i++){
      int r = i*32 + w*8 + sr;
      async_cp16(Bt + (long long)r * g.ldb + sq*8, lB + (i*256 + w*64) * 8);
    }
    __syncthreads();
    #pragma unroll
    for (int kk = 0; kk < 64; kk += 32){
      const int qf = (kk + fk) >> 3;
      int ra = w*16 + fm;
      s16x8 af = *(const s16x8*)(lA + (ra*8 + (qf ^ (ra & 7))) * 8);
      #pragma unroll
      for (int ni=0; ni<16; ni++){
        int r = ni*16 + fm;
        s16x8 bfr = *(const s16x8*)(lB + (r*8 + (qf ^ (r & 7))) * 8);
        acc[ni] = __builtin_amdgcn_mfma_f32_16x16x32_bf16(af, bfr, acc[ni], 0, 0, 0);
      }
    }
  }

  u16* Cb = g.C + (long long)z * g.c_z;
  const u16* biasp = g.bias ? g.bias + (long long)z * g.bias_z : (const u16*)0;
  #pragma unroll
  for (int ni=0; ni<16; ni++){
    int n = ni*16 + fm;
    float bb = 0.0f;
    if (g.cbias) bb = g.cbias[n];
    else if (biasp) bb = b2f(biasp[n]);
    #pragma unroll
    for (int r=0; r<4; r++){
      long long b = arow0 + w*16 + (lane>>4)*4 + r;
      float v = acc[ni][r] * g.scale + bb;
      if (g.addm) v += b2f(g.addm[b*256 + n]);
      if (g.relu) v = v > 0.0f ? v : 0.0f;
      Cb[b * (long long)g.ldc + n] = f2b(v);
    }
  }
}

// ---------- stage5b fused: ch in regs -> wc2 dot -> sigmoid -> scores only ----------
__global__ __launch_bounds__(256, 4) void gemm_score(GArgs g){
  alignas(16) __shared__ u16 lA[64*64];
  alignas(16) __shared__ u16 lB[256*64];
  const int tid  = threadIdx.x;
  const int lane = tid & 63;
  const int w    = tid >> 6;
  const int z    = blockIdx.z;

  const u16* Bbase = g.B;

  f32x4 acc[16];
  #pragma unroll
  for (int j=0;j<16;j++)
    #pragma unroll
    for (int r=0;r<4;r++) acc[j][r] = 0.0f;

  const int fm = lane & 15;
  const int fk = (lane >> 4) * 8;
  const long long arow0 = (long long)blockIdx.x * 64;

  const int sr = lane >> 3;
  const int sq = (lane & 7) ^ sr;

  for (int k0 = 0; k0 < g.K; k0 += 64){
    const u16* At = g.A + (long long)z * g.a_z + k0;
    const u16* Bt = Bbase + k0;
    __syncthreads();
    #pragma unroll
    for (int i=0;i<2;i++){
      int r = i*32 + w*8 + sr;
      async_cp16(At + (arow0 + r) * (long long)g.lda + sq*8, lA + (i*256 + w*64) * 8);
    }
    #pragma unroll
    for (int i=0;i<8;i++){
      int r = i*32 + w*8 + sr;
      async_cp16(Bt + (long long)r * g.ldb + sq*8, lB + (i*256 + w*64) * 8);
    }
    __syncthreads();
    #pragma unroll
    for (int kk = 0; kk < 64; kk += 32){
      const int qf = (kk + fk) >> 3;
      int ra = w*16 + fm;
      s16x8 af = *(const s16x8*)(lA + (ra*8 + (qf ^ (ra & 7))) * 8);
      #pragma unroll
      for (int ni=0; ni<16; ni++){
        int r = ni*16 + fm;
        s16x8 bfr = *(const s16x8*)(lB + (r*8 + (qf ^ (r & 7))) * 8);
        acc[ni] = __builtin_amdgcn_mfma_f32_16x16x32_bf16(af, bfr, acc[ni], 0, 0, 0);
      }
    }
  }

  // epilogue: ch = relu(acc + qctx + bc1); p[r] = sum_n ch*wc2[n]; score = sigmoid(p + bc2 via cbias[256]?)
  float p[4] = {0.f, 0.f, 0.f, 0.f};
  #pragma unroll
  for (int ni=0; ni<16; ni++){
    int n = ni*16 + fm;
    float bb = b2f(g.bias[n]);
    float wcv = b2f(g.wc2[n]);
    #pragma unroll
    for (int r=0; r<4; r++){
      long long b = arow0 + w*16 + (lane>>4)*4 + r;
      float v = acc[ni][r] + bb + b2f(g.addm[b*256 + n]);
      v = v > 0.0f ? v : 0.0f;
      p[r] += v * wcv;
    }
  }
  // reduce across the 16 lanes of the quad (fm = low 4 bits)
  #pragma unroll
  for (int r=0; r<4; r++){
    #pragma unroll
    for (int off=1; off<16; off<<=1) p[r] += __shfl_xor(p[r], off);
  }
  if (fm == 0){
    float bc2f = g.cbias[0];
    #pragma unroll
    for (int r=0; r<4; r++){
      long long b = arow0 + w*16 + (lane>>4)*4 + r;
      g.scores[(long long)z*BB + b] = 1.0f / (1.0f + __expf(-(p[r] + bc2f)));
    }
  }
}

// WB[n=(s*256+o)][k=(t*256+d)] = sum_e Wo[s,t,o,e]*Wv[s,t,e,d], zeroed on s==t diagonal.
__global__ __launch_bounds__(256, 2) void build_wb(const float* Wo, const float* Wv, u16* WB){
  alignas(16) __shared__ u16 lA[128*64];
  alignas(16) __shared__ u16 lB[128*64];
  const int tid  = threadIdx.x;
  const int lane = tid & 63;
  const int w    = tid >> 6;
  const int z = blockIdx.z, s = z >> 3, t = z & 7;
  const long long zoff = (long long)z * 65536;

  f32x4 acc[4][4];
  #pragma unroll
  for (int i=0;i<4;i++)
    #pragma unroll
    for (int j=0;j<4;j++)
      #pragma unroll
      for (int r=0;r<4;r++) acc[i][j][r] = 0.0f;

  const int wr = (w >> 1) * 64, wc = (w & 1) * 64;
  const int fm = lane & 15;
  const int fk = (lane >> 4) * 8;

  int srow[4], sq[4];
  #pragma unroll
  for (int i=0;i<4;i++){
    int c = i*256 + tid;
    srow[i] = c >> 3;
    sq[i]   = (c & 7) ^ (srow[i] & 7);
  }

  for (int k0 = 0; k0 < 256; k0 += 64){
    s16x8 va[4], vt[4];
    #pragma unroll
    for (int i=0;i<4;i++){
      long long aidx = zoff + (long long)(blockIdx.x*128 + srow[i]) * 256 + k0 + sq[i]*8;
      va[i] = load8_f32(Wo, aidx);
    }
    #pragma unroll
    for (int j=0;j<4;j++){
      int id = j*256 + tid;
      int e  = id >> 4;
      int dc = (id & 15) * 8;
      long long bidx = zoff + (long long)(k0 + e) * 256 + blockIdx.y*128 + dc;
      vt[j] = load8_f32(Wv, bidx);
    }
    __syncthreads();
    #pragma unroll
    for (int i=0;i<4;i++){
      int c = i*256 + tid;
      *(s16x8*)(lA + c*8) = va[i];
    }
    #pragma unroll
    for (int j=0;j<4;j++){
      int id = j*256 + tid;
      int e  = id >> 4;
      int dc = (id & 15) * 8;
      #pragma unroll
      for (int u=0; u<8; u++){
        int d = dc + u;
        lB[(d*8 + ((e>>3) ^ (d & 7)))*8 + (e & 7)] = (u16)vt[j][u];
      }
    }
    __syncthreads();
    #pragma unroll
    for (int kk = 0; kk < 64; kk += 32){
      s16x8 af[4], bfr[4];
      const int qf = (kk + fk) >> 3;
      #pragma unroll
      for (int mi=0; mi<4; mi++){
        int r = wr + mi*16 + fm;
        af[mi] = *(const s16x8*)(lA + (r*8 + (qf ^ (r & 7))) * 8);
      }
      #pragma unroll
      for (int ni=0; ni<4; ni++){
        int r = wc + ni*16 + fm;
        bfr[ni] = *(const s16x8*)(lB + (r*8 + (qf ^ (r & 7))) * 8);
      }
      #pragma unroll
      for (int mi=0; mi<4; mi++)
        #pragma unroll
        for (int ni=0; ni<4; ni++)
          acc[mi][ni] = __builtin_amdgcn_mfma_f32_16x16x32_bf16(af[mi], bfr[ni], acc[mi][ni], 0, 0, 0);
    }
    __syncthreads();
  }
  const int diag = (s == t);
  #pragma unroll
  for (int mi=0; mi<4; mi++){
    #pragma unroll
    for (int ni=0; ni<4; ni++){
      int d = blockIdx.y*128 + wc + ni*16 + fm;
      #pragma unroll
      for (int r=0; r<4; r++){
        int o = blockIdx.x*128 + wr + mi*16 + (lane>>4)*4 + r;
        float v = diag ? 0.0f : acc[mi][ni][r];
        WB[(long long)(s*256 + o) * 2048 + t*256 + d] = f2b(v);
      }
    }
  }
}

// cb[s*256+o] += (1/7)*( dot(bv[s,t,:], Wo[s,t,o,:]) + bo[s,t,o] )  for t != s. cb zeroed first.
// grid (64 pairs, 4 o-chunks); wave-per-row, lane-per-float4: fully coalesced.
__global__ __launch_bounds__(256) void cb_kernel(const float* bv, const float* Wo, const float* bo, float* cb){
  int z = blockIdx.x, s = z >> 3, t = z & 7;
  if (s == t) return;
  int lane = threadIdx.x & 63, w = threadIdx.x >> 6;
  float4 bvv = *(const float4*)(bv + (long long)z*256 + lane*4);
  #pragma unroll
  for (int i=0; i<16; i++){
    int row = blockIdx.y*64 + w*16 + i;
    float4 wv4 = *(const float4*)(Wo + (long long)z*65536 + (long long)row*256 + lane*4);
    float p = wv4.x*bvv.x + wv4.y*bvv.y + wv4.z*bvv.z + wv4.w*bvv.w;
    #pragma unroll
    for (int off=32; off>0; off>>=1) p += __shfl_xor(p, off);
    if (lane == 0)
      atomicAdd(&cb[s*256 + row], (p + bo[(long long)z*256 + row]) * (1.0f/7.0f));
  }
}

// out[b,:] = (1/8) sum_m fused[m,b,:] * scores[m,b]
__global__ __launch_bounds__(256) void final_gate(const u16* fused, const float* scores, float* out){
  int b = blockIdx.x;
  int tid = threadIdx.x;
  float sc[8];
  #pragma unroll
  for (int m=0; m<8; m++) sc[m] = scores[(long long)m*BB + b];
  float acc = 0.0f;
  #pragma unroll
  for (int m=0; m<8; m++)
    acc += b2f(fused[((long long)m*BB + b)*256 + tid]) * sc[m];
  out[(long long)b*256 + tid] = acc * 0.125f;
}

extern "C" void kernel_launch(void* const* d_in, const int* in_sizes, int n_in,
                              void* d_out, int out_size, void* d_ws, size_t ws_size,
                              hipStream_t stream){
  const float* x   = (const float*)d_in[0];
  const float* q   = (const float*)d_in[1];
  const float* Wv  = (const float*)d_in[2];
  const float* bv  = (const float*)d_in[3];
  const float* Wo  = (const float*)d_in[4];
  const float* bo  = (const float*)d_in[5];
  const float* W1  = (const float*)d_in[6];
  const float* b1  = (const float*)d_in[7];
  const float* W2  = (const float*)d_in[8];
  const float* b2  = (const float*)d_in[9];
  const float* Wc1 = (const float*)d_in[10];
  const float* bc1 = (const float*)d_in[11];
  const float* wc2 = (const float*)d_in[12];
  const float* bc2 = (const float*)d_in[13];

  char* ws = (char*)d_ws;
  u16*   xb    = (u16*)(ws + 0LL);            // 32MB; dead after stage3 -> fused
  u16*   qb    = (u16*)(ws + 33554432LL);     // 4MB
  u16*   cross = (u16*)(ws + 37748736LL);     // 32MB
  u16*   hid   = (u16*)(ws + 71303168LL);     // 32MB
  u16*   WB    = (u16*)(ws + 104857600LL);    // 8MB; dead after stage2 -> qctx+scores
  u16*   W1b   = (u16*)(ws + 113246208LL);    // 2MB
  u16*   W2b   = (u16*)(ws + 115343360LL);    // 1MB
  u16*   Wc1b  = (u16*)(ws + 116391936LL);    // 256KB
  u16*   b1b   = (u16*)(ws + 116654080LL);    // 4KB
  u16*   b2b   = (u16*)(ws + 116658176LL);    // 4KB
  u16*   bc1b  = (u16*)(ws + 116662272LL);    // 512B
  u16*   wc2b  = (u16*)(ws + 116662784LL);    // 512B
  float* bc2f  = (float*)(ws + 116663296LL);  // 64B (fp32 copy via cbias path)
  float* cb    = (float*)(ws + 116663424LL);  // 8KB
  u16*   fused = xb;
  u16*   qctx  = WB;                                   // 4MB (dead WB)
  float* scores = (float*)(ws + 104857600LL + 4194304LL); // 256KB (dead WB upper half)

  ConvArgs ca{};
  ca.src[0]=x;   ca.dst[0]=xb;   ca.n[0]=MMOD*BB*DD;
  ca.src[1]=q;   ca.dst[1]=qb;   ca.n[1]=BB*DD;
  ca.src[2]=W1;  ca.dst[2]=W1b;  ca.n[2]=MMOD*DD*2*DD;
  ca.src[3]=W2;  ca.dst[3]=W2b;  ca.n[3]=MMOD*DD*DD;
  ca.src[4]=Wc1; ca.dst[4]=Wc1b; ca.n[4]=DD*2*DD;
  ca.src[5]=b1;  ca.dst[5]=b1b;  ca.n[5]=MMOD*DD;
  ca.src[6]=b2;  ca.dst[6]=b2b;  ca.n[6]=MMOD*DD;
  ca.src[7]=bc1; ca.dst[7]=bc1b; ca.n[7]=DD;
  ca.src[8]=wc2; ca.dst[8]=wc2b; ca.n[8]=DD;
  ca.src[9]=bc2; ca.dst[9]=bc1b; ca.n[9]=0;   // unused slot (bc2 handled below)
  convert_kernel<<<1024, 256, 0, stream>>>(ca);
  hipMemcpyAsync(bc2f, bc2, sizeof(float), hipMemcpyDeviceToDevice, stream);

  hipMemsetAsync(cb, 0, 2048*sizeof(float), stream);
  build_wb<<<dim3(2,2,64), 256, 0, stream>>>(Wo, Wv, WB);
  cb_kernel<<<dim3(64,4), 256, 0, stream>>>(bv, Wo, bo, cb);

  const long long BD = (long long)BB * DD;

  // Stage 2 (fat): cross[s,b,o] = (1/7) sum_k xb'[b,k] * WB[(s,o),k] + cb
  GArgs g2{};
  g2.A = xb; g2.a_z = 0; g2.a_piece = BD; g2.lda = 256; g2.A2 = 0; g2.a2_z = 0;
  g2.B = WB; g2.b_z = 0; g2.ldb = 2048;
  g2.C = cross; g2.c_z = 0; g2.c_npiece = BD; g2.ldc = 256;
  g2.bias = 0; g2.bias_z = 0; g2.cbias = cb; g2.addm = 0; g2.wc2 = 0; g2.scores = 0;
  g2.scale = 1.0f/7.0f; g2.K = 2048; g2.relu = 0;
  gemm_bt<<<dim3(64,16,1), 256, 0, stream>>>(g2);

  // Stage 5a (thin): qctx = qb @ Wc1[:, :256]^T   (into dead WB)
  GArgs g5a{};
  g5a.A = qb; g5a.a_z = 0; g5a.a_piece = 0; g5a.lda = 256; g5a.A2 = 0; g5a.a2_z = 0;
  g5a.B = Wc1b; g5a.b_z = 0; g5a.ldb = 512;
  g5a.C = qctx; g5a.c_z = 0; g5a.c_npiece = 0; g5a.ldc = 256;
  g5a.bias = 0; g5a.bias_z = 0; g5a.cbias = 0; g5a.addm = 0; g5a.wc2 = 0; g5a.scores = 0;
  g5a.scale = 1.0f; g5a.K = 256; g5a.relu = 0;
  gemm_thin<<<dim3(128,1,1), 256, 0, stream>>>(g5a);

  // Stage 3 (thin): hid[m] = relu([xb[m] | cross[m]] @ W1[m]^T + b1[m])
  GArgs g3{};
  g3.A = xb; g3.a_z = BD; g3.a_piece = 0; g3.lda = 256; g3.A2 = cross; g3.a2_z = BD;
  g3.B = W1b; g3.b_z = (long long)DD*2*DD; g3.ldb = 512;
  g3.C = hid; g3.c_z = BD; g3.c_npiece = 0; g3.ldc = 256;
  g3.bias = b1b; g3.bias_z = 256; g3.cbias = 0; g3.addm = 0; g3.wc2 = 0; g3.scores = 0;
  g3.scale = 1.0f; g3.K = 512; g3.relu = 1;
  gemm_thin<<<dim3(128,1,8), 256, 0, stream>>>(g3);

  // Stage 4 (thin): fused[m] = hid[m] @ W2[m]^T + b2[m]   (overwrites dead xb)
  GArgs g4{};
  g4.A = hid; g4.a_z = BD; g4.a_piece = 0; g4.lda = 256; g4.A2 = 0; g4.a2_z = 0;
  g4.B = W2b; g4.b_z = (long long)DD*DD; g4.ldb = 256;
  g4.C = fused; g4.c_z = BD; g4.c_npiece = 0; g4.ldc = 256;
  g4.bias = b2b; g4.bias_z = 256; g4.cbias = 0; g4.addm = 0; g4.wc2 = 0; g4.scores = 0;
  g4.scale = 1.0f; g4.K = 256; g4.relu = 0;
  gemm_thin<<<dim3(128,1,8), 256, 0, stream>>>(g4);

  // Stage 5b (score): scores[m,b] = sigmoid(wc2 . relu(fused[m] @ Wc1[:,256:]^T + qctx + bc1) + bc2)
  GArgs g5b{};
  g5b.A = fused; g5b.a_z = BD; g5b.a_piece = 0; g5b.lda = 256; g5b.A2 = 0; g5b.a2_z = 0;
  g5b.B = Wc1b + 256; g5b.b_z = 0; g5b.ldb = 512;
  g5b.C = 0; g5b.c_z = 0; g5b.c_npiece = 0; g5b.ldc = 0;
  g5b.bias = bc1b; g5b.bias_z = 0; g5b.cbias = bc2f; g5b.addm = qctx;
  g5b.wc2 = wc2b; g5b.scores = scores;
  g5b.scale = 1.0f; g5b.K = 256; g5b.relu = 1;
  gemm_score<<<dim3(128,1,8), 256, 0, stream>>>(g5b);

  final_gate<<<dim3(BB), 256, 0, stream>>>(fused, scores, (float*)d_out);

  (void)in_sizes; (void)n_in; (void)out_size; (void)ws_size;
}